// Round 4
// baseline (645.500 us; speedup 1.0000x reference)
//
#include <hip/hip_runtime.h>

// Blocks2Matrix, gather formulation, 2-barrier prefetch-all schedule.
//
//   values[s, mu, p, q] : s*320 + mu*64 + p*8 + q   (S, 5, 8, 8) f32
//   cg[a, b, m]         : a*25 + b*5 + m            (5, 5, 5)    f32
//   block[R, C] = sum_m cg[R%5, C%5, m] * values[s, m, R/5, C/5]
//   H[sys, i*40+R, j*40+C] += block[R,C]        (direct)
//   H[sys, j*40+C, i*40+R] += block[R,C]        (transpose)
//
// Tile (sy,I,J), local element (rr,cc):
//   direct entries  (i=I, j=J):  block[rr][cc] = sum cg[rr%5,cc%5,m] v[m,rr/5,cc/5]
//   transpose       (j=I, i=J):  block[cc][rr] = sum cg[cc%5,rr%5,m] v[m,cc/5,rr/5]
// One workgroup per tile -> plain stores, no d_out memset needed.

#define SS      32768
#define MU      5
#define NORB    40
#define NSYS    16
#define NATOMS  64
#define NDIM    2560
#define NBINS   (NSYS * NATOMS * NATOMS)   // 65536
#define CAP     16                          // Poisson(1): P(n>16) ~ 1e-14
#define MAXOVF  8192

// ws layout (bytes):
//   [0,        262144)  counts[NBINS]
//   [262144,   262148)  ovf_count
//   [262272,   327808)  ovf entries int2[MAXOVF]
//   [524288,  4718592)  bins[NBINS*CAP]
#define WS_NEEDED   (524288 + (size_t)NBINS * CAP * 4)

__global__ __launch_bounds__(256) void b2m_fill(
    const int* __restrict__ sys_idx, const int* __restrict__ i_idx,
    const int* __restrict__ j_idx,
    int* __restrict__ counts, int* __restrict__ bins,
    int* __restrict__ ovf_cnt, int2* __restrict__ ovf)
{
    int s = blockIdx.x * blockDim.x + threadIdx.x;
    if (s >= SS) return;
    int sy = sys_idx[s], i = i_idx[s], j = j_idx[s];

    int bd = (sy * NATOMS + i) * NATOMS + j;           // direct tile
    int pos = atomicAdd(&counts[bd], 1);
    if (pos < CAP) bins[bd * CAP + pos] = s;
    else { int o = atomicAdd(ovf_cnt, 1); if (o < MAXOVF) ovf[o] = make_int2(bd, s); }

    int bt = (sy * NATOMS + j) * NATOMS + i;           // transpose tile
    int st = s | 0x10000;
    pos = atomicAdd(&counts[bt], 1);
    if (pos < CAP) bins[bt * CAP + pos] = st;
    else { int o = atomicAdd(ovf_cnt, 1); if (o < MAXOVF) ovf[o] = make_int2(bt, st); }
}

__global__ __launch_bounds__(320) void b2m_gather(
    const float* __restrict__ values, const float* __restrict__ cg,
    const int* __restrict__ counts, const int* __restrict__ bins,
    float* __restrict__ H)
{
    __shared__ float sv[CAP * 320];   // 20 KB: all prefetched entry values
    __shared__ float scg[125];
    __shared__ int   sent[CAP];

    const int bin = blockIdx.x;
    const int tid = threadIdx.x;

    // uniform (blockIdx-derived) -> scalar load
    int n = counts[bin];
    if (n > CAP) n = CAP;

    if (tid < 125) scg[tid] = cg[tid];
    if (tid < CAP) sent[tid] = bins[bin * CAP + tid];
    __syncthreads();                              // barrier 1: scg + sent ready

    // prefetch ALL entries' values concurrently (float4, 80 lanes/entry)
    const int kg = tid / 80;                      // entry sub-group 0..3
    const int f  = tid - kg * 80;                 // float4 index 0..79
    for (int u = 0; u < n; u += 4) {
        int k = u + kg;
        if (k < n) {
            int s = sent[k] & 0xFFFF;
            reinterpret_cast<float4*>(sv)[k * 80 + f] =
                reinterpret_cast<const float4*>(values)[s * 80 + f];
        }
    }
    __syncthreads();                              // barrier 2: sv ready

    // per-thread element geometry: e = it*320 + tid
    int od[5], ot[5], id_[5], it_[5], rr[5], cc[5];
    #pragma unroll
    for (int it = 0; it < 5; ++it) {
        int e = it * 320 + tid;
        int r = e / 40, c = e - r * 40;
        int p = r / 5, a = r - p * 5;
        int q = c / 5, b = c - q * 5;
        rr[it] = r; cc[it] = c;
        od[it]  = p * 8 + q;                      // sv offset, direct
        ot[it]  = q * 8 + p;                      // sv offset, transpose
        id_[it] = (a * 5 + b) * 5;                // scg base, direct
        it_[it] = (b * 5 + a) * 5;                // scg base, transpose
    }

    float acc[5] = {0.f, 0.f, 0.f, 0.f, 0.f};
    for (int k = 0; k < n; ++k) {
        const int ent = sent[k];
        const float* vk = sv + k * 320;
        if ((ent & 0x10000) == 0) {
            #pragma unroll
            for (int it = 0; it < 5; ++it)
                #pragma unroll
                for (int m = 0; m < 5; ++m)
                    acc[it] = fmaf(scg[id_[it] + m], vk[m * 64 + od[it]], acc[it]);
        } else {
            #pragma unroll
            for (int it = 0; it < 5; ++it)
                #pragma unroll
                for (int m = 0; m < 5; ++m)
                    acc[it] = fmaf(scg[it_[it] + m], vk[m * 64 + ot[it]], acc[it]);
        }
    }

    const int jj = bin & 63, ii = (bin >> 6) & 63, sy = bin >> 12;
    float* Hs = H + ((size_t)sy * NDIM + (size_t)ii * NORB) * NDIM + (size_t)jj * NORB;
    #pragma unroll
    for (int it = 0; it < 5; ++it)
        Hs[(size_t)rr[it] * NDIM + cc[it]] = acc[it];
}

__global__ __launch_bounds__(256) void b2m_ovf_apply(
    const float* __restrict__ values, const float* __restrict__ cg,
    const int* __restrict__ ovf_cnt, const int2* __restrict__ ovf,
    float* __restrict__ H)
{
    int n = *ovf_cnt;
    if (n > MAXOVF) n = MAXOVF;
    for (int k = blockIdx.x; k < n; k += gridDim.x) {
        int  bin = ovf[k].x;
        int  ent = ovf[k].y;
        int  s   = ent & 0xFFFF;
        bool tr  = (ent >> 16) != 0;
        int  j = bin & 63, i = (bin >> 6) & 63, sy = bin >> 12;
        const float* vs = values + (size_t)s * (MU * 64);
        float* Hs = H + (size_t)sy * NDIM * NDIM;
        for (int e = threadIdx.x; e < 1600; e += blockDim.x) {
            int rr = e / 40, cc = e - rr * 40;
            int R = tr ? cc : rr, C = tr ? rr : cc;
            int p = R / 5, a = R - p * 5;
            int q = C / 5, b = C - q * 5;
            float v = 0.f;
            for (int m = 0; m < 5; ++m)
                v = fmaf(cg[(a * 5 + b) * 5 + m], vs[m * 64 + p * 8 + q], v);
            atomicAdd(Hs + (size_t)(i * NORB + rr) * NDIM + (j * NORB + cc), v);
        }
    }
}

// ---- round-1 fallback (used only if ws_size is too small) ----
__global__ __launch_bounds__(320) void b2m_scatter(
    const float* __restrict__ values, const float* __restrict__ cg,
    const int* __restrict__ sys_idx, const int* __restrict__ i_idx,
    const int* __restrict__ j_idx, float* __restrict__ H)
{
    __shared__ float sv[MU * 64];
    __shared__ float scg[125];
    const int s = blockIdx.x, tid = threadIdx.x;
    if (tid < MU * 64) sv[tid] = values[(size_t)s * (MU * 64) + tid];
    if (tid < 125) scg[tid] = cg[tid];
    __syncthreads();
    const int sys = sys_idx[s], i = i_idx[s], j = j_idx[s];
    float* Hs = H + (size_t)sys * NDIM * NDIM;
    const int rowbase = i * NORB, colbase = j * NORB;
    #pragma unroll
    for (int it = 0; it < 5; ++it) {
        const int e = tid + it * 320;
        const int r = e / 40, c = e - r * 40;
        const int p = r / 5, a = r - p * 5, q = c / 5, b = c - q * 5;
        float v = 0.f;
        #pragma unroll
        for (int m = 0; m < 5; ++m)
            v = fmaf(scg[(a * 5 + b) * 5 + m], sv[m * 64 + p * 8 + q], v);
        atomicAdd(Hs + (size_t)(rowbase + r) * NDIM + (colbase + c), v);
    }
    #pragma unroll
    for (int it = 0; it < 5; ++it) {
        const int e = tid + it * 320;
        const int c2 = e / 40, r2 = e - c2 * 40;
        const int p = r2 / 5, a = r2 - p * 5, q = c2 / 5, b = c2 - q * 5;
        float v = 0.f;
        #pragma unroll
        for (int m = 0; m < 5; ++m)
            v = fmaf(scg[(a * 5 + b) * 5 + m], sv[m * 64 + p * 8 + q], v);
        atomicAdd(Hs + (size_t)(colbase + c2) * NDIM + (rowbase + r2), v);
    }
}

extern "C" void kernel_launch(void* const* d_in, const int* in_sizes, int n_in,
                              void* d_out, int out_size, void* d_ws, size_t ws_size,
                              hipStream_t stream) {
    const float* values  = (const float*)d_in[0];
    const float* cg      = (const float*)d_in[1];
    const int*   sys_idx = (const int*)d_in[2];
    const int*   i_idx   = (const int*)d_in[3];
    const int*   j_idx   = (const int*)d_in[4];
    float*       H       = (float*)d_out;

    if (ws_size >= WS_NEEDED) {
        char* ws      = (char*)d_ws;
        int*  counts  = (int*)ws;                       // 256 KB
        int*  ovf_cnt = (int*)(ws + 262144);
        int2* ovf     = (int2*)(ws + 262272);
        int*  bins    = (int*)(ws + 524288);

        // zero counts + ovf header (bins are guarded by counts)
        hipMemsetAsync(ws, 0, 262400, stream);

        b2m_fill<<<(SS + 255) / 256, 256, 0, stream>>>(
            sys_idx, i_idx, j_idx, counts, bins, ovf_cnt, ovf);
        b2m_gather<<<NBINS, 320, 0, stream>>>(values, cg, counts, bins, H);
        b2m_ovf_apply<<<64, 256, 0, stream>>>(values, cg, ovf_cnt, ovf, H);
    } else {
        hipMemsetAsync(H, 0, (size_t)out_size * sizeof(float), stream);
        b2m_scatter<<<SS, 320, 0, stream>>>(values, cg, sys_idx, i_idx, j_idx, H);
    }
}

// Round 5
// 595.574 us; speedup vs baseline: 1.0838x; 1.0838x over previous
//
#include <hip/hip_runtime.h>

// Blocks2Matrix, persistent-block gather with per-bin software pipeline.
//
//   values[s, mu, p, q] : s*320 + mu*64 + p*8 + q   (S, 5, 8, 8) f32
//   cg[a, b, m]         : a*25 + b*5 + m            (5, 5, 5)    f32
//   block[R, C] = sum_m cg[R%5, C%5, m] * values[s, m, R/5, C/5]
//   H[sys, i*40+R, j*40+C] += block[R,C]        (direct)
//   H[sys, j*40+C, i*40+R] += block[R,C]        (transpose)
//
// Tile (sy,I,J), local element (rr,cc):
//   direct (i=I,j=J):   += sum_m cg[rr%5,cc%5,m] v[m, rr/5, cc/5]
//   transpose (j=I,i=J):+= sum_m cg[cc%5,rr%5,m] v[m, cc/5, rr/5]
// One owner per tile -> plain stores, no d_out memset.
//
// Round-4 lesson: 65536 tiny blocks = launch/latency bound (272us, 21% BW).
// Now: 1536 persistent blocks (6/CU), ~43 bins each, pipelined:
//   barrier; load values(t+1)->regs, meta(t+2)->regs; compute(t); regs->LDS.

#define SS      32768
#define MU      5
#define NORB    40
#define NSYS    16
#define NATOMS  64
#define NDIM    2560
#define NBINS   (NSYS * NATOMS * NATOMS)   // 65536
#define CAP     16                          // Poisson(1): P(n>16) ~ 1e-14
#define SC      4                           // staged entries (P(n>4) = 0.37%, tail path)
#define MAXOVF  8192
#define GBLK    1536                        // 256 CU * 6 blocks (320 thr -> 30 waves/CU)
#define PERB    ((NBINS + GBLK - 1) / GBLK) // 43 bins per block

// ws layout (bytes):
//   [0,        262144)  counts[NBINS]
//   [262144,   262148)  ovf_count
//   [262272,   327808)  ovf entries int2[MAXOVF]
//   [524288,  4718592)  bins[NBINS*CAP]
#define WS_NEEDED   (524288 + (size_t)NBINS * CAP * 4)

__global__ __launch_bounds__(256) void b2m_fill(
    const int* __restrict__ sys_idx, const int* __restrict__ i_idx,
    const int* __restrict__ j_idx,
    int* __restrict__ counts, int* __restrict__ bins,
    int* __restrict__ ovf_cnt, int2* __restrict__ ovf)
{
    int s = blockIdx.x * blockDim.x + threadIdx.x;
    if (s >= SS) return;
    int sy = sys_idx[s], i = i_idx[s], j = j_idx[s];

    int bd = (sy * NATOMS + i) * NATOMS + j;           // direct tile
    int pos = atomicAdd(&counts[bd], 1);
    if (pos < CAP) bins[bd * CAP + pos] = s;
    else { int o = atomicAdd(ovf_cnt, 1); if (o < MAXOVF) ovf[o] = make_int2(bd, s); }

    int bt = (sy * NATOMS + j) * NATOMS + i;           // transpose tile
    int st = s | 0x10000;
    pos = atomicAdd(&counts[bt], 1);
    if (pos < CAP) bins[bt * CAP + pos] = st;
    else { int o = atomicAdd(ovf_cnt, 1); if (o < MAXOVF) ovf[o] = make_int2(bt, st); }
}

// accumulate one entry into acc[0..4] from source pointer VK (LDS or global)
#define ACCUM_DIR(VK)                                                  \
    _Pragma("unroll")                                                  \
    for (int it = 0; it < 5; ++it) {                                   \
        _Pragma("unroll")                                              \
        for (int m = 0; m < 5; ++m)                                    \
            acc[it] = fmaf(scg[idd[it] + m], (VK)[m * 64 + od[it]], acc[it]); \
    }
#define ACCUM_TR(VK)                                                   \
    _Pragma("unroll")                                                  \
    for (int it = 0; it < 5; ++it) {                                   \
        _Pragma("unroll")                                              \
        for (int m = 0; m < 5; ++m)                                    \
            acc[it] = fmaf(scg[idt[it] + m], (VK)[m * 64 + ot[it]], acc[it]); \
    }

__global__ __launch_bounds__(320) void b2m_gather(
    const float* __restrict__ values, const float* __restrict__ cg,
    const int* __restrict__ counts, const int* __restrict__ bins,
    float* __restrict__ H)
{
    __shared__ float sv[2][SC * 320];   // 10 KB ping-pong value staging
    __shared__ int   slist[3][CAP];     // entry lists, triple-buffered
    __shared__ int   scnt[3];
    __shared__ float scg[125];

    const int tid = threadIdx.x;
    const int b0  = blockIdx.x * PERB;
    const int b1  = min(b0 + PERB, NBINS);
    if (b0 >= NBINS) return;            // uniform early-exit

    if (tid < 125) scg[tid] = cg[tid];

    // per-thread geometry: element e = it*320 + tid of the 40x40 tile
    int od[5], ot[5], idd[5], idt[5], soff[5];
    #pragma unroll
    for (int it = 0; it < 5; ++it) {
        int e = it * 320 + tid;
        int r = e / 40, c = e - r * 40;
        int p = r / 5, a = r - p * 5;
        int q = c / 5, b = c - q * 5;
        soff[it] = r * NDIM + c;
        od[it]  = p * 8 + q;            // value offset, direct
        ot[it]  = q * 8 + p;            // value offset, transpose
        idd[it] = (a * 5 + b) * 5;      // cg base, direct
        idt[it] = (b * 5 + a) * 5;      // cg base, transpose
    }

    const int kq = tid / 80;            // which staged entry this thread loads
    const int f4 = tid - kq * 80;       // float4 index within entry (0..79)

    // ---- prologue: meta for b0 (slot0) and b0+1 (slot1) ----
    if (tid < CAP) slist[0][tid] = bins[b0 * CAP + tid];
    if (tid == 317) scnt[0] = min(counts[b0], CAP);
    if (b0 + 1 < b1) {
        if (tid < CAP) slist[1][tid] = bins[(b0 + 1) * CAP + tid];
        if (tid == 318) scnt[1] = min(counts[b0 + 1], CAP);
    } else if (tid == 318) scnt[1] = 0;
    __syncthreads();

    // stage bin b0 into sv[0] (visible after first loop-top barrier)
    {
        int n0 = scnt[0];
        if (kq < n0) {
            int s = slist[0][kq] & 0xFFFF;
            reinterpret_cast<float4*>(&sv[0][0])[tid] =
                reinterpret_cast<const float4*>(values)[s * 80 + f4];
        }
    }

    for (int t = b0; t < b1; ++t) {
        const int cur  = (t - b0) & 1;
        const int s3   = (t - b0) % 3;
        const int s3n  = (t + 1 - b0) % 3;
        const int s3nn = (t + 2 - b0) % 3;
        __syncthreads();   // sv[cur] + slist[s3n] ready; prior readers of sv[cur^1]/slist[s3nn] done

        // issue value loads for bin t+1 (regs; latency hidden under compute)
        float4 stg;
        int n1 = 0;
        const bool have1 = (t + 1 < b1);
        if (have1) {
            n1 = scnt[s3n];
            if (kq < n1) {
                int s = slist[s3n][kq] & 0xFFFF;
                stg = reinterpret_cast<const float4*>(values)[s * 80 + f4];
            }
        }
        // issue meta loads for bin t+2 (regs)
        int ment = 0, mcnt = 0;
        const bool have2 = (t + 2 < b1);
        if (have2) {
            if (tid < CAP) ment = bins[(t + 2) * CAP + tid];
            if (tid == 0)  mcnt = counts[t + 2];
        }

        // ---- compute bin t ----
        const int n = scnt[s3];
        float acc[5] = {0.f, 0.f, 0.f, 0.f, 0.f};
        for (int k = 0; k < n; ++k) {
            const int ent = slist[s3][k];
            if (k < SC) {
                const float* vk = &sv[cur][k * 320];
                if ((ent & 0x10000) == 0) { ACCUM_DIR(vk) } else { ACCUM_TR(vk) }
            } else {   // rare tail (P=0.37%): read straight from global
                const float* vg = values + (size_t)(ent & 0xFFFF) * 320;
                if ((ent & 0x10000) == 0) { ACCUM_DIR(vg) } else { ACCUM_TR(vg) }
            }
        }

        // retire staged regs -> LDS for next bin (compiler waits vmcnt here)
        if (have1 && kq < n1)
            reinterpret_cast<float4*>(&sv[cur ^ 1][0])[tid] = stg;
        if (have2) {
            if (tid < CAP) slist[s3nn][tid] = ment;
            if (tid == 0)  scnt[s3nn] = min(mcnt, CAP);
        }

        // ---- store tile t ----
        const int jj = t & 63, ii = (t >> 6) & 63, sy = t >> 12;
        float* Hs = H + ((size_t)sy * NDIM + (size_t)ii * NORB) * NDIM + (size_t)jj * NORB;
        #pragma unroll
        for (int it = 0; it < 5; ++it)
            Hs[soff[it]] = acc[it];
    }
}

__global__ __launch_bounds__(256) void b2m_ovf_apply(
    const float* __restrict__ values, const float* __restrict__ cg,
    const int* __restrict__ ovf_cnt, const int2* __restrict__ ovf,
    float* __restrict__ H)
{
    int n = *ovf_cnt;
    if (n > MAXOVF) n = MAXOVF;
    for (int k = blockIdx.x; k < n; k += gridDim.x) {
        int  bin = ovf[k].x;
        int  ent = ovf[k].y;
        int  s   = ent & 0xFFFF;
        bool tr  = (ent >> 16) != 0;
        int  j = bin & 63, i = (bin >> 6) & 63, sy = bin >> 12;
        const float* vs = values + (size_t)s * (MU * 64);
        float* Hs = H + (size_t)sy * NDIM * NDIM;
        for (int e = threadIdx.x; e < 1600; e += blockDim.x) {
            int rr = e / 40, cc = e - rr * 40;
            int R = tr ? cc : rr, C = tr ? rr : cc;
            int p = R / 5, a = R - p * 5;
            int q = C / 5, b = C - q * 5;
            float v = 0.f;
            for (int m = 0; m < 5; ++m)
                v = fmaf(cg[(a * 5 + b) * 5 + m], vs[m * 64 + p * 8 + q], v);
            atomicAdd(Hs + (size_t)(i * NORB + rr) * NDIM + (j * NORB + cc), v);
        }
    }
}

// ---- round-1 fallback (used only if ws_size is too small) ----
__global__ __launch_bounds__(320) void b2m_scatter(
    const float* __restrict__ values, const float* __restrict__ cg,
    const int* __restrict__ sys_idx, const int* __restrict__ i_idx,
    const int* __restrict__ j_idx, float* __restrict__ H)
{
    __shared__ float svv[MU * 64];
    __shared__ float scg[125];
    const int s = blockIdx.x, tid = threadIdx.x;
    if (tid < MU * 64) svv[tid] = values[(size_t)s * (MU * 64) + tid];
    if (tid < 125) scg[tid] = cg[tid];
    __syncthreads();
    const int sys = sys_idx[s], i = i_idx[s], j = j_idx[s];
    float* Hs = H + (size_t)sys * NDIM * NDIM;
    const int rowbase = i * NORB, colbase = j * NORB;
    #pragma unroll
    for (int it = 0; it < 5; ++it) {
        const int e = tid + it * 320;
        const int r = e / 40, c = e - r * 40;
        const int p = r / 5, a = r - p * 5, q = c / 5, b = c - q * 5;
        float v = 0.f;
        #pragma unroll
        for (int m = 0; m < 5; ++m)
            v = fmaf(scg[(a * 5 + b) * 5 + m], svv[m * 64 + p * 8 + q], v);
        atomicAdd(Hs + (size_t)(rowbase + r) * NDIM + (colbase + c), v);
    }
    #pragma unroll
    for (int it = 0; it < 5; ++it) {
        const int e = tid + it * 320;
        const int c2 = e / 40, r2 = e - c2 * 40;
        const int p = r2 / 5, a = r2 - p * 5, q = c2 / 5, b = c2 - q * 5;
        float v = 0.f;
        #pragma unroll
        for (int m = 0; m < 5; ++m)
            v = fmaf(scg[(a * 5 + b) * 5 + m], svv[m * 64 + p * 8 + q], v);
        atomicAdd(Hs + (size_t)(colbase + c2) * NDIM + (rowbase + r2), v);
    }
}

extern "C" void kernel_launch(void* const* d_in, const int* in_sizes, int n_in,
                              void* d_out, int out_size, void* d_ws, size_t ws_size,
                              hipStream_t stream) {
    const float* values  = (const float*)d_in[0];
    const float* cg      = (const float*)d_in[1];
    const int*   sys_idx = (const int*)d_in[2];
    const int*   i_idx   = (const int*)d_in[3];
    const int*   j_idx   = (const int*)d_in[4];
    float*       H       = (float*)d_out;

    if (ws_size >= WS_NEEDED) {
        char* ws      = (char*)d_ws;
        int*  counts  = (int*)ws;                       // 256 KB
        int*  ovf_cnt = (int*)(ws + 262144);
        int2* ovf     = (int2*)(ws + 262272);
        int*  bins    = (int*)(ws + 524288);

        // zero counts + ovf header (bins are guarded by counts)
        hipMemsetAsync(ws, 0, 262400, stream);

        b2m_fill<<<(SS + 255) / 256, 256, 0, stream>>>(
            sys_idx, i_idx, j_idx, counts, bins, ovf_cnt, ovf);
        b2m_gather<<<GBLK, 320, 0, stream>>>(values, cg, counts, bins, H);
        b2m_ovf_apply<<<64, 256, 0, stream>>>(values, cg, ovf_cnt, ovf, H);
    } else {
        hipMemsetAsync(H, 0, (size_t)out_size * sizeof(float), stream);
        b2m_scatter<<<SS, 320, 0, stream>>>(values, cg, sys_idx, i_idx, j_idx, H);
    }
}